// Round 8
// baseline (71.735 us; speedup 1.0000x reference)
//
#include <hip/hip_runtime.h>
#include <math.h>

constexpr int M_TOK = 8;
constexpr int N_OUT = 8192;
constexpr int K_IN  = 8192;
constexpr int KG    = 64;   // K / G, G = 128
constexpr int R_N   = 4;    // output rows per wave

typedef int   i32x4 __attribute__((ext_vector_type(4)));
typedef float f32x4 __attribute__((ext_vector_type(4)));

// ---------------- Kernel 1: per-token symmetric int8 fake-quant ----------------
__global__ __launch_bounds__(1024) void act_quant_kernel(const float* __restrict__ x,
                                                         float* __restrict__ xq) {
    const int row = blockIdx.x;
    const f32x4* xr = reinterpret_cast<const f32x4*>(x + (size_t)row * K_IN);
    f32x4* oq = reinterpret_cast<f32x4*>(xq + (size_t)row * K_IN);
    const int tid = threadIdx.x;

    f32x4 v0 = xr[tid * 2];
    f32x4 v1 = xr[tid * 2 + 1];

    float m = fmaxf(
        fmaxf(fmaxf(fabsf(v0.x), fabsf(v0.y)), fmaxf(fabsf(v0.z), fabsf(v0.w))),
        fmaxf(fmaxf(fabsf(v1.x), fabsf(v1.y)), fmaxf(fabsf(v1.z), fabsf(v1.w))));

    #pragma unroll
    for (int off = 32; off; off >>= 1) m = fmaxf(m, __shfl_xor(m, off));

    __shared__ float smax[16];
    if ((tid & 63) == 0) smax[tid >> 6] = m;
    __syncthreads();
    float mm = smax[0];
    #pragma unroll
    for (int i = 1; i < 16; ++i) mm = fmaxf(mm, smax[i]);

    const float s = fmaxf(mm / 127.0f, 1e-8f);

    auto quant = [&](float v) -> float {
        float q = rintf(v / s);              // numpy round = half-to-even
        q = fminf(fmaxf(q, -127.0f), 127.0f);
        return q * s;
    };

    f32x4 o0, o1;
    o0.x = quant(v0.x); o0.y = quant(v0.y); o0.z = quant(v0.z); o0.w = quant(v0.w);
    o1.x = quant(v1.x); o1.y = quant(v1.y); o1.z = quant(v1.z); o1.w = quant(v1.w);
    oq[tid * 2]     = o0;
    oq[tid * 2 + 1] = o1;
}

// ---------------- Kernel 2: dequant + skinny GEMM ----------------
// EXACT round-1 structure (68.5 us baseline). Single change: weight loads are
// non-temporal (no L1/L2/L3 allocation). Weights are a 256 MiB zero-reuse
// cyclic stream that thrashes the exactly-256-MiB Infinity Cache; allocation
// is pure overhead. Ledger: manual prefetch+rotate REGRESSED (r3, likely
// spills); split-K (r4), xq-LDS (r5), fusion (r6), global_load_lds (r7) NULL.
__global__ __launch_bounds__(256) void qlin_kernel(const float* __restrict__ xq,
                                                   const int* __restrict__ qw,
                                                   const float* __restrict__ scales,
                                                   const float* __restrict__ bias,
                                                   float* __restrict__ out) {
    const int wave = blockIdx.x * 4 + (threadIdx.x >> 6);
    const int lane = threadIdx.x & 63;
    const int n0 = wave * R_N;
    const int lk = lane * 4;

    float acc[R_N][M_TOK];
    #pragma unroll
    for (int r = 0; r < R_N; ++r)
        #pragma unroll
        for (int m = 0; m < M_TOK; ++m) acc[r][m] = 0.0f;

    for (int kb = 0; kb < K_IN; kb += 256) {
        const int k = kb + lk;
        const int g = k >> 7;  // group index; 4 consecutive k share one group

        f32x4 xv[M_TOK];
        #pragma unroll
        for (int m = 0; m < M_TOK; ++m)
            xv[m] = *reinterpret_cast<const f32x4*>(xq + (size_t)m * K_IN + k);

        #pragma unroll
        for (int r = 0; r < R_N; ++r) {
            const i32x4 c = __builtin_nontemporal_load(
                reinterpret_cast<const i32x4*>(qw + (size_t)(n0 + r) * K_IN + k));
            const float sc = scales[(size_t)(n0 + r) * KG + g];
            const float w0 = (float)c.x * sc;
            const float w1 = (float)c.y * sc;
            const float w2 = (float)c.z * sc;
            const float w3 = (float)c.w * sc;
            #pragma unroll
            for (int m = 0; m < M_TOK; ++m) {
                float a = acc[r][m];
                a = fmaf(w0, xv[m].x, a);
                a = fmaf(w1, xv[m].y, a);
                a = fmaf(w2, xv[m].z, a);
                a = fmaf(w3, xv[m].w, a);
                acc[r][m] = a;
            }
        }
    }

    // full butterfly reduce -> every lane holds each (r,m) total
    #pragma unroll
    for (int r = 0; r < R_N; ++r)
        #pragma unroll
        for (int m = 0; m < M_TOK; ++m) {
            float v = acc[r][m];
            #pragma unroll
            for (int off = 32; off; off >>= 1) v += __shfl_xor(v, off);
            acc[r][m] = v;
        }

    // lane (r*8 + m) writes out[m][n0+r]
    if (lane < R_N * M_TOK) {
        const int rsel = lane >> 3;
        const int msel = lane & 7;
        float myv = 0.0f;
        #pragma unroll
        for (int r = 0; r < R_N; ++r)
            #pragma unroll
            for (int m = 0; m < M_TOK; ++m)
                if (r == rsel && m == msel) myv = acc[r][m];
        out[(size_t)msel * N_OUT + n0 + rsel] = myv + bias[n0 + rsel];
    }
}

extern "C" void kernel_launch(void* const* d_in, const int* in_sizes, int n_in,
                              void* d_out, int out_size, void* d_ws, size_t ws_size,
                              hipStream_t stream) {
    const float* x      = (const float*)d_in[0];
    const int*   qw     = (const int*)d_in[1];
    const float* scales = (const float*)d_in[2];
    const float* bias   = (const float*)d_in[3];
    float* out = (float*)d_out;
    float* xq  = (float*)d_ws;  // M*K floats = 256 KiB scratch

    act_quant_kernel<<<M_TOK, 1024, 0, stream>>>(x, xq);

    const int waves  = N_OUT / R_N;        // 2048
    const int blocks = waves / 4;          // 512 blocks x 256 threads
    qlin_kernel<<<blocks, 256, 0, stream>>>(xq, qw, scales, bias, out);
}

// Round 9
// 59.595 us; speedup vs baseline: 1.2037x; 1.2037x over previous
//
#include <hip/hip_runtime.h>
#include <math.h>

constexpr int M_TOK = 8;
constexpr int N_OUT = 8192;
constexpr int K_IN  = 8192;
constexpr int KG    = 64;   // K / G, G = 128
constexpr int R_N   = 4;    // output rows per wave
constexpr int NT    = 32;   // k-chunks of 256

typedef int   i32x4 __attribute__((ext_vector_type(4)));
typedef float f32x4 __attribute__((ext_vector_type(4)));

// ---------------- Kernel 1: per-token symmetric int8 fake-quant ----------------
__global__ __launch_bounds__(1024) void act_quant_kernel(const float* __restrict__ x,
                                                         float* __restrict__ xq) {
    const int row = blockIdx.x;
    const f32x4* xr = reinterpret_cast<const f32x4*>(x + (size_t)row * K_IN);
    f32x4* oq = reinterpret_cast<f32x4*>(xq + (size_t)row * K_IN);
    const int tid = threadIdx.x;

    f32x4 v0 = xr[tid * 2];
    f32x4 v1 = xr[tid * 2 + 1];

    float m = fmaxf(
        fmaxf(fmaxf(fabsf(v0.x), fabsf(v0.y)), fmaxf(fabsf(v0.z), fabsf(v0.w))),
        fmaxf(fmaxf(fabsf(v1.x), fabsf(v1.y)), fmaxf(fabsf(v1.z), fabsf(v1.w))));

    #pragma unroll
    for (int off = 32; off; off >>= 1) m = fmaxf(m, __shfl_xor(m, off));

    __shared__ float smax[16];
    if ((tid & 63) == 0) smax[tid >> 6] = m;
    __syncthreads();
    float mm = smax[0];
    #pragma unroll
    for (int i = 1; i < 16; ++i) mm = fmaxf(mm, smax[i]);

    const float s = fmaxf(mm / 127.0f, 1e-8f);

    auto quant = [&](float v) -> float {
        float q = rintf(v / s);              // numpy round = half-to-even
        q = fminf(fmaxf(q, -127.0f), 127.0f);
        return q * s;
    };

    f32x4 o0, o1;
    o0.x = quant(v0.x); o0.y = quant(v0.y); o0.z = quant(v0.z); o0.w = quant(v0.w);
    o1.x = quant(v1.x); o1.y = quant(v1.y); o1.z = quant(v1.z); o1.w = quant(v1.w);
    oq[tid * 2]     = o0;
    oq[tid * 2 + 1] = o1;
}

// ---------------- Kernel 2: dequant + skinny GEMM, phase-staggered k ----------------
// EXACT round-1 structure except each wave starts its k sweep at a per-wave
// phase and wraps (decorrelates instantaneous HBM channel usage across the
// device). Accumulation order per wave is fixed -> deterministic.
// Ledger: prefetch+nt REGRESSED (r3); nt-alone REGRESSED (r8); split-K (r4),
// xq-LDS (r5), fusion (r6), global_load_lds (r7) NULL — all pinned ~4.4 TB/s.
__global__ __launch_bounds__(256) void qlin_kernel(const float* __restrict__ xq,
                                                   const int* __restrict__ qw,
                                                   const float* __restrict__ scales,
                                                   const float* __restrict__ bias,
                                                   float* __restrict__ out) {
    const int wave = blockIdx.x * 4 + (threadIdx.x >> 6);
    const int lane = threadIdx.x & 63;
    const int n0 = wave * R_N;
    const int lk = lane * 4;

    float acc[R_N][M_TOK];
    #pragma unroll
    for (int r = 0; r < R_N; ++r)
        #pragma unroll
        for (int m = 0; m < M_TOK; ++m) acc[r][m] = 0.0f;

    const int phase = (wave & (NT - 1)) * 256;   // per-wave k start

    for (int t = 0; t < NT; ++t) {
        const int kb = (phase + t * 256) & (K_IN - 1);
        const int k = kb + lk;
        const int g = k >> 7;  // group index; 4 consecutive k share one group

        f32x4 xv[M_TOK];
        #pragma unroll
        for (int m = 0; m < M_TOK; ++m)
            xv[m] = *reinterpret_cast<const f32x4*>(xq + (size_t)m * K_IN + k);

        #pragma unroll
        for (int r = 0; r < R_N; ++r) {
            const i32x4 c =
                *reinterpret_cast<const i32x4*>(qw + (size_t)(n0 + r) * K_IN + k);
            const float sc = scales[(size_t)(n0 + r) * KG + g];
            const float w0 = (float)c.x * sc;
            const float w1 = (float)c.y * sc;
            const float w2 = (float)c.z * sc;
            const float w3 = (float)c.w * sc;
            #pragma unroll
            for (int m = 0; m < M_TOK; ++m) {
                float a = acc[r][m];
                a = fmaf(w0, xv[m].x, a);
                a = fmaf(w1, xv[m].y, a);
                a = fmaf(w2, xv[m].z, a);
                a = fmaf(w3, xv[m].w, a);
                acc[r][m] = a;
            }
        }
    }

    // full butterfly reduce -> every lane holds each (r,m) total
    #pragma unroll
    for (int r = 0; r < R_N; ++r)
        #pragma unroll
        for (int m = 0; m < M_TOK; ++m) {
            float v = acc[r][m];
            #pragma unroll
            for (int off = 32; off; off >>= 1) v += __shfl_xor(v, off);
            acc[r][m] = v;
        }

    // lane (r*8 + m) writes out[m][n0+r]
    if (lane < R_N * M_TOK) {
        const int rsel = lane >> 3;
        const int msel = lane & 7;
        float myv = 0.0f;
        #pragma unroll
        for (int r = 0; r < R_N; ++r)
            #pragma unroll
            for (int m = 0; m < M_TOK; ++m)
                if (r == rsel && m == msel) myv = acc[r][m];
        out[(size_t)msel * N_OUT + n0 + rsel] = myv + bias[n0 + rsel];
    }
}

extern "C" void kernel_launch(void* const* d_in, const int* in_sizes, int n_in,
                              void* d_out, int out_size, void* d_ws, size_t ws_size,
                              hipStream_t stream) {
    const float* x      = (const float*)d_in[0];
    const int*   qw     = (const int*)d_in[1];
    const float* scales = (const float*)d_in[2];
    const float* bias   = (const float*)d_in[3];
    float* out = (float*)d_out;
    float* xq  = (float*)d_ws;  // M*K floats = 256 KiB scratch

    act_quant_kernel<<<M_TOK, 1024, 0, stream>>>(x, xq);

    const int waves  = N_OUT / R_N;        // 2048
    const int blocks = waves / 4;          // 512 blocks x 256 threads
    qlin_kernel<<<blocks, 256, 0, stream>>>(xq, qw, scales, bias, out);
}